// Round 1
// baseline (1468.082 us; speedup 1.0000x reference)
//
#include <hip/hip_runtime.h>
#include <hip/hip_bf16.h>
#include <stdint.h>

// Problem constants
#define T_DIM 2048
#define B_DIM 8
#define D_DIM 1024
#define NSTATE 1024
#define BLKSZ 8
#define NB 128
#define M_DIM (T_DIM * B_DIM)   // 16384
#define N_DIM (3 * NSTATE)      // 3072 (k | v | q concatenated)
#define K_DIM D_DIM             // 1024

typedef __bf16 bf16x8 __attribute__((ext_vector_type(8)));
typedef float f32x4 __attribute__((ext_vector_type(4)));
typedef unsigned int uintx4 __attribute__((ext_vector_type(4)));

__device__ __forceinline__ unsigned short f2bf(float f) {
  unsigned u = __float_as_uint(f);
  u = (u + 0x7FFFu + ((u >> 16) & 1u)) >> 16;  // RNE
  return (unsigned short)u;
}
__device__ __forceinline__ float bf2f(unsigned short h) {
  return __uint_as_float(((unsigned)h) << 16);
}

// ---------------- Kernel 1: fp32 -> bf16 conversion of x and Wcat ----------
// Rows 0..M_DIM-1: x [16384][1024] -> xb. Rows M_DIM..M_DIM+3071: Wk|Wv|Wq -> wb.
__global__ __launch_bounds__(256) void convert_kernel(
    const float* __restrict__ x, const float* __restrict__ Wk,
    const float* __restrict__ Wv, const float* __restrict__ Wq,
    unsigned short* __restrict__ xb, unsigned short* __restrict__ wb) {
  size_t idx = (size_t)blockIdx.x * blockDim.x + threadIdx.x;  // one per 4 elems
  size_t row = idx >> 8;          // 256 chunks of 4 per 1024-row
  int c4 = (int)(idx & 255) * 4;
  const float* src;
  unsigned short* dst;
  if (row < (size_t)M_DIM) {
    src = x + row * K_DIM;
    dst = xb + row * K_DIM;
  } else {
    size_t r = row - M_DIM;
    const float* w = (r < 1024) ? Wk : (r < 2048 ? Wv : Wq);
    src = w + (r & 1023) * K_DIM;
    dst = wb + r * K_DIM;
  }
  float4 v = *(const float4*)(src + c4);
  ushort4 o;
  o.x = f2bf(v.x); o.y = f2bf(v.y); o.z = f2bf(v.z); o.w = f2bf(v.w);
  *(ushort4*)(dst + c4) = o;
}

// ---------------- Kernel 2: bf16 MFMA GEMM  C[M][N] = X[M][K] * W[N][K]^T ---
#define BM 128
#define BN 128
#define BK 32
#define LDK 40  // padded LDS row stride in elems (80 B = 5*16 B, keeps 16B align)

__global__ __launch_bounds__(256) void gemm_kernel(
    const unsigned short* __restrict__ A,     // [M][K] bf16
    const unsigned short* __restrict__ Bmat,  // [N][K] bf16
    unsigned short* __restrict__ C) {         // [M][N] bf16
  __shared__ unsigned short As[BM * LDK];
  __shared__ unsigned short Bs[BN * LDK];

  const int tid = threadIdx.x;
  const int nTiles = N_DIM / BN;  // 24
  const int nTile = blockIdx.x % nTiles;
  const int mTile = blockIdx.x / nTiles;
  const int m0 = mTile * BM, n0 = nTile * BN;

  const int lane = tid & 63, wave = tid >> 6;
  const int wm = wave >> 1, wn = wave & 1;  // 2x2 wave grid, 64x64 per wave
  const int l15 = lane & 15, quad = lane >> 4;

  f32x4 acc[4][4];
#pragma unroll
  for (int mi = 0; mi < 4; mi++)
#pragma unroll
    for (int ni = 0; ni < 4; ni++) acc[mi][ni] = (f32x4){0.f, 0.f, 0.f, 0.f};

  // staging: 512 chunks of 8 bf16 per tile; thread t does chunks t and t+256
  const int srow = tid >> 2;          // 0..63
  const int scol = (tid & 3) * 8;     // 0,8,16,24

  for (int k0 = 0; k0 < K_DIM; k0 += BK) {
    const uintx4 a0 = *(const uintx4*)(A + (size_t)(m0 + srow) * K_DIM + k0 + scol);
    const uintx4 a1 = *(const uintx4*)(A + (size_t)(m0 + srow + 64) * K_DIM + k0 + scol);
    const uintx4 b0 = *(const uintx4*)(Bmat + (size_t)(n0 + srow) * K_DIM + k0 + scol);
    const uintx4 b1 = *(const uintx4*)(Bmat + (size_t)(n0 + srow + 64) * K_DIM + k0 + scol);
    __syncthreads();  // previous iter's reads done before overwrite
    *(uintx4*)(As + srow * LDK + scol) = a0;
    *(uintx4*)(As + (srow + 64) * LDK + scol) = a1;
    *(uintx4*)(Bs + srow * LDK + scol) = b0;
    *(uintx4*)(Bs + (srow + 64) * LDK + scol) = b1;
    __syncthreads();

    bf16x8 af[4], bfr[4];
#pragma unroll
    for (int mi = 0; mi < 4; mi++) {
      uintx4 r = *(const uintx4*)(As + (wm * 64 + mi * 16 + l15) * LDK + quad * 8);
      af[mi] = __builtin_bit_cast(bf16x8, r);
    }
#pragma unroll
    for (int ni = 0; ni < 4; ni++) {
      uintx4 r = *(const uintx4*)(Bs + (wn * 64 + ni * 16 + l15) * LDK + quad * 8);
      bfr[ni] = __builtin_bit_cast(bf16x8, r);
    }
#pragma unroll
    for (int mi = 0; mi < 4; mi++)
#pragma unroll
      for (int ni = 0; ni < 4; ni++)
        acc[mi][ni] = __builtin_amdgcn_mfma_f32_16x16x32_bf16(
            af[mi], bfr[ni], acc[mi][ni], 0, 0, 0);
  }

  // Epilogue: D[row=(quad*4+r)][col=l15] per 16x16 tile
#pragma unroll
  for (int mi = 0; mi < 4; mi++) {
#pragma unroll
    for (int ni = 0; ni < 4; ni++) {
      int col = n0 + wn * 64 + ni * 16 + l15;
#pragma unroll
      for (int r = 0; r < 4; r++) {
        int rowg = m0 + wm * 64 + mi * 16 + quad * 4 + r;
        C[(size_t)rowg * N_DIM + col] = f2bf(acc[mi][ni][r]);
      }
    }
  }
}

// ---------------- Kernel 3: sequential scan -------------------------------
// One wave per (b, nb). Lane (i,j) = (lane>>3, lane&7) holds S[i][j].
__global__ __launch_bounds__(64) void scan_kernel(
    const unsigned short* __restrict__ kvq,  // [T*B][3072] bf16 (k|v|q)
    float* __restrict__ out) {               // outputs then S_final
  const int blk = blockIdx.x;
  const int nb = blk & (NB - 1);
  const int b = blk >> 7;
  const int lane = threadIdx.x;
  const int i = lane >> 3, j = lane & 7;

  const unsigned short* base = kvq + (size_t)b * N_DIM;
  const int kcol = nb * BLKSZ + j;
  const int vcol = NSTATE + nb * BLKSZ + i;
  const int qcol = 2 * NSTATE + nb * BLKSZ + j;
  const size_t stepStride = (size_t)B_DIM * N_DIM;  // elems per t

  float S = 0.f;
  float kj = bf2f(base[kcol]);
  float vi = bf2f(base[vcol]);
  float qj = bf2f(base[qcol]);
  float* outp = out + (size_t)b * NSTATE + nb * BLKSZ + i;

  for (int t = 0; t < T_DIM; ++t) {
    float nk = 0.f, nv = 0.f, nq = 0.f;
    if (t + 1 < T_DIM) {  // software prefetch of next step
      const unsigned short* nxt = base + (size_t)(t + 1) * stepStride;
      nk = bf2f(nxt[kcol]);
      nv = bf2f(nxt[vcol]);
      nq = bf2f(nxt[qcol]);
    }
    // ||k|| over j within this row's 8 lanes
    float s = kj * kj;
    s += __shfl_xor(s, 1); s += __shfl_xor(s, 2); s += __shfl_xor(s, 4);
    float kn = kj / (sqrtf(s) + 1e-6f);
    // retrieved_i = sum_j S[i][j] * kn[j]
    float p = S * kn;
    p += __shfl_xor(p, 1); p += __shfl_xor(p, 2); p += __shfl_xor(p, 4);
    float delta = vi - p;
    // S = tanh(S + delta_i * kn_j); tanh(x) = 1 - 2/(exp(2x)+1) (no NaN at +inf)
    float pre = S + delta * kn;
    float e = __expf(2.f * pre);
    S = 1.f - 2.f / (e + 1.f);
    // Sq_i = sum_j S[i][j] * q[j]
    float z = S * qj;
    z += __shfl_xor(z, 1); z += __shfl_xor(z, 2); z += __shfl_xor(z, 4);
    if (j == 0) {
      float sig = 1.f / (1.f + __expf(-z));
      outp[(size_t)t * B_DIM * NSTATE] = z * z * sig;  // Sq * silu(Sq)
    }
    kj = nk; vi = nv; qj = nq;
  }
  // S_final: [B][NB][8][8] appended after outputs
  out[(size_t)T_DIM * B_DIM * NSTATE + (size_t)(b * NB + nb) * 64 + lane] = S;
}

// ---------------- launch ---------------------------------------------------
extern "C" void kernel_launch(void* const* d_in, const int* in_sizes, int n_in,
                              void* d_out, int out_size, void* d_ws,
                              size_t ws_size, hipStream_t stream) {
  const float* x = (const float*)d_in[0];
  const float* Wk = (const float*)d_in[1];
  const float* Wv = (const float*)d_in[2];
  const float* Wq = (const float*)d_in[3];
  float* out = (float*)d_out;

  unsigned short* xb = (unsigned short*)d_ws;                  // 32 MB
  unsigned short* wb = xb + (size_t)M_DIM * K_DIM;             // 6 MB
  unsigned short* kvq = wb + (size_t)N_DIM * K_DIM;            // 96 MB

  // convert: (M_DIM + N_DIM) rows * 256 chunks / 256 threads
  convert_kernel<<<M_DIM + N_DIM, 256, 0, stream>>>(x, Wk, Wv, Wq, xb, wb);
  gemm_kernel<<<(M_DIM / BM) * (N_DIM / BN), 256, 0, stream>>>(xb, wb, kvq);
  scan_kernel<<<B_DIM * NB, 64, 0, stream>>>(kvq, out);
}

// Round 2
// 939.762 us; speedup vs baseline: 1.5622x; 1.5622x over previous
//
#include <hip/hip_runtime.h>
#include <hip/hip_bf16.h>
#include <stdint.h>

// Problem constants
#define T_DIM 2048
#define B_DIM 8
#define D_DIM 1024
#define NSTATE 1024
#define BLKSZ 8
#define NB 128
#define M_DIM (T_DIM * B_DIM)   // 16384
#define N_DIM (3 * NSTATE)      // 3072 (k | v | q concatenated)
#define K_DIM D_DIM             // 1024

typedef __bf16 bf16x8 __attribute__((ext_vector_type(8)));
typedef float f32x4 __attribute__((ext_vector_type(4)));
typedef unsigned int uintx4 __attribute__((ext_vector_type(4)));

__device__ __forceinline__ unsigned short f2bf(float f) {
  unsigned u = __float_as_uint(f);
  u = (u + 0x7FFFu + ((u >> 16) & 1u)) >> 16;  // RNE
  return (unsigned short)u;
}
__device__ __forceinline__ float bf2f(unsigned short h) {
  return __uint_as_float(((unsigned)h) << 16);
}

// ---------------- Kernel 1: fp32 -> bf16 conversion of x and Wcat ----------
__global__ __launch_bounds__(256) void convert_kernel(
    const float* __restrict__ x, const float* __restrict__ Wk,
    const float* __restrict__ Wv, const float* __restrict__ Wq,
    unsigned short* __restrict__ xb, unsigned short* __restrict__ wb) {
  size_t idx = (size_t)blockIdx.x * blockDim.x + threadIdx.x;  // one per 4 elems
  size_t row = idx >> 8;          // 256 chunks of 4 per 1024-row
  int c4 = (int)(idx & 255) * 4;
  const float* src;
  unsigned short* dst;
  if (row < (size_t)M_DIM) {
    src = x + row * K_DIM;
    dst = xb + row * K_DIM;
  } else {
    size_t r = row - M_DIM;
    const float* w = (r < 1024) ? Wk : (r < 2048 ? Wv : Wq);
    src = w + (r & 1023) * K_DIM;
    dst = wb + r * K_DIM;
  }
  float4 v = *(const float4*)(src + c4);
  ushort4 o;
  o.x = f2bf(v.x); o.y = f2bf(v.y); o.z = f2bf(v.z); o.w = f2bf(v.w);
  *(ushort4*)(dst + c4) = o;
}

// ---------------- Kernel 2: bf16 MFMA GEMM  C[M][N] = X[M][K] * W[N][K]^T ---
#define BM 128
#define BN 128
#define BK 32
#define LDK 40  // padded LDS row stride in elems

__global__ __launch_bounds__(256) void gemm_kernel(
    const unsigned short* __restrict__ A,     // [M][K] bf16
    const unsigned short* __restrict__ Bmat,  // [N][K] bf16
    unsigned short* __restrict__ C) {         // [M][N] bf16
  __shared__ unsigned short As[BM * LDK];
  __shared__ unsigned short Bs[BN * LDK];

  const int tid = threadIdx.x;
  const int nTiles = N_DIM / BN;  // 24
  const int nTile = blockIdx.x % nTiles;
  const int mTile = blockIdx.x / nTiles;
  const int m0 = mTile * BM, n0 = nTile * BN;

  const int lane = tid & 63, wave = tid >> 6;
  const int wm = wave >> 1, wn = wave & 1;  // 2x2 wave grid, 64x64 per wave
  const int l15 = lane & 15, quad = lane >> 4;

  f32x4 acc[4][4];
#pragma unroll
  for (int mi = 0; mi < 4; mi++)
#pragma unroll
    for (int ni = 0; ni < 4; ni++) acc[mi][ni] = (f32x4){0.f, 0.f, 0.f, 0.f};

  const int srow = tid >> 2;          // 0..63
  const int scol = (tid & 3) * 8;     // 0,8,16,24

  for (int k0 = 0; k0 < K_DIM; k0 += BK) {
    const uintx4 a0 = *(const uintx4*)(A + (size_t)(m0 + srow) * K_DIM + k0 + scol);
    const uintx4 a1 = *(const uintx4*)(A + (size_t)(m0 + srow + 64) * K_DIM + k0 + scol);
    const uintx4 b0 = *(const uintx4*)(Bmat + (size_t)(n0 + srow) * K_DIM + k0 + scol);
    const uintx4 b1 = *(const uintx4*)(Bmat + (size_t)(n0 + srow + 64) * K_DIM + k0 + scol);
    __syncthreads();
    *(uintx4*)(As + srow * LDK + scol) = a0;
    *(uintx4*)(As + (srow + 64) * LDK + scol) = a1;
    *(uintx4*)(Bs + srow * LDK + scol) = b0;
    *(uintx4*)(Bs + (srow + 64) * LDK + scol) = b1;
    __syncthreads();

    bf16x8 af[4], bfr[4];
#pragma unroll
    for (int mi = 0; mi < 4; mi++) {
      uintx4 r = *(const uintx4*)(As + (wm * 64 + mi * 16 + l15) * LDK + quad * 8);
      af[mi] = __builtin_bit_cast(bf16x8, r);
    }
#pragma unroll
    for (int ni = 0; ni < 4; ni++) {
      uintx4 r = *(const uintx4*)(Bs + (wn * 64 + ni * 16 + l15) * LDK + quad * 8);
      bfr[ni] = __builtin_bit_cast(bf16x8, r);
    }
#pragma unroll
    for (int mi = 0; mi < 4; mi++)
#pragma unroll
      for (int ni = 0; ni < 4; ni++)
        acc[mi][ni] = __builtin_amdgcn_mfma_f32_16x16x32_bf16(
            af[mi], bfr[ni], acc[mi][ni], 0, 0, 0);
  }

#pragma unroll
  for (int mi = 0; mi < 4; mi++) {
#pragma unroll
    for (int ni = 0; ni < 4; ni++) {
      int col = n0 + wn * 64 + ni * 16 + l15;
#pragma unroll
      for (int r = 0; r < 4; r++) {
        int rowg = m0 + wm * 64 + mi * 16 + quad * 4 + r;
        C[(size_t)rowg * N_DIM + col] = f2bf(acc[mi][ni][r]);
      }
    }
  }
}

// ---------------- Kernel 3: sequential scan, shuffle-free ------------------
// One lane per (chain, row i). chain = (b, nb). Lane holds S[i][0..7] in regs.
// Wave = 8 chains (8 consecutive nb of one b) x 8 rows -> 64 lanes.
// rows are independent given k: delta_i = v_i - rs*dot(S[i],k);
// S[i][j] = tanh(S[i][j] + (delta_i*rs)*k[j]).  No cross-lane ops at all.

__device__ __forceinline__ void unpack8(uintx4 u, float* f) {
#pragma unroll
  for (int n = 0; n < 4; n++) {
    unsigned w = u[n];
    f[2 * n] = __uint_as_float(w << 16);
    f[2 * n + 1] = __uint_as_float(w & 0xffff0000u);
  }
}

__device__ __forceinline__ float dot8(const float* a, const float* b) {
  float s01 = fmaf(a[1], b[1], a[0] * b[0]);
  float s23 = fmaf(a[3], b[3], a[2] * b[2]);
  float s45 = fmaf(a[5], b[5], a[4] * b[4]);
  float s67 = fmaf(a[7], b[7], a[6] * b[6]);
  return (s01 + s23) + (s45 + s67);
}

#define C_2LOG2E 2.8853900817779268f   // 2*log2(e)
#define C_LOG2E  1.4426950408889634f

__global__ __launch_bounds__(64) void scan_kernel(
    const unsigned short* __restrict__ kvq,  // [T*B][3072] bf16 (k|v|q)
    float* __restrict__ out) {               // outputs then S_final
  const int blk = blockIdx.x;          // 0..127
  const int b = blk >> 4;              // 0..7
  const int nb0 = (blk & 15) * 8;      // first nb of this wave
  const int lane = threadIdx.x;
  const int c = lane >> 3;             // chain within wave (0..7)
  const int i = lane & 7;              // row within 8x8 state
  const int nb = nb0 + c;

  const size_t stride = (size_t)B_DIM * N_DIM;  // elems per t
  const unsigned short* kp = kvq + (size_t)b * N_DIM + nb * BLKSZ;
  const unsigned short* qp = kp + 2 * NSTATE;
  const unsigned short* vp = kp + NSTATE + i;

  float S[8];
#pragma unroll
  for (int j = 0; j < 8; j++) S[j] = 0.f;

  float kf[8], qf[8], vi;
  {
    uintx4 k4 = *(const uintx4*)kp;
    uintx4 q4 = *(const uintx4*)qp;
    vi = bf2f(*vp);
    unpack8(k4, kf);
    unpack8(q4, qf);
  }

  // output pointer: out[t][b][nb*8 + i]
  float* outp = out + (size_t)b * NSTATE + (size_t)nb * BLKSZ + i;

  for (int t = 0; t < T_DIM; ++t) {
    const size_t adv = (t + 1 < T_DIM) ? stride : 0;
    uintx4 nk4 = *(const uintx4*)(kp + adv);
    uintx4 nq4 = *(const uintx4*)(qp + adv);
    unsigned short nv = *(vp + adv);
    kp += adv; qp += adv; vp += adv;

    // rs = 1/(||k|| + 1e-6)
    float nrm = dot8(kf, kf);
    float rs = __builtin_amdgcn_rcpf(__builtin_amdgcn_sqrtf(nrm) + 1e-6f);
    // retrieved_i = rs * dot(S_i, k);  delta_i = v_i - retrieved
    float r = dot8(S, kf);
    float scale = (vi - r * rs) * rs;   // delta_i * rs
    // S_j = tanh(S_j + scale*k_j)  via  1 - 2/(exp2(x*2log2e)+1)
#pragma unroll
    for (int j = 0; j < 8; j++) {
      float pre = fmaf(scale, kf[j], S[j]);
      float e = __builtin_amdgcn_exp2f(pre * C_2LOG2E);
      S[j] = fmaf(-2.f, __builtin_amdgcn_rcpf(e + 1.f), 1.f);
    }
    // z_i = dot(S_i, q);  out = z^2 * sigmoid(z)
    float z = dot8(S, qf);
    float sig = __builtin_amdgcn_rcpf(1.f + __builtin_amdgcn_exp2f(-z * C_LOG2E));
    outp[(size_t)t * B_DIM * NSTATE] = z * z * sig;

    unpack8(nk4, kf);
    unpack8(nq4, qf);
    vi = bf2f(nv);
  }

  // S_final: [B][NB][8][8]; lane (c,i) holds row i -> 8 consecutive floats
  float* sf = out + (size_t)T_DIM * B_DIM * NSTATE +
              (size_t)(b * NB + nb) * 64 + i * 8;
  *(float4*)(sf + 0) = make_float4(S[0], S[1], S[2], S[3]);
  *(float4*)(sf + 4) = make_float4(S[4], S[5], S[6], S[7]);
}

// ---------------- launch ---------------------------------------------------
extern "C" void kernel_launch(void* const* d_in, const int* in_sizes, int n_in,
                              void* d_out, int out_size, void* d_ws,
                              size_t ws_size, hipStream_t stream) {
  const float* x = (const float*)d_in[0];
  const float* Wk = (const float*)d_in[1];
  const float* Wv = (const float*)d_in[2];
  const float* Wq = (const float*)d_in[3];
  float* out = (float*)d_out;

  unsigned short* xb = (unsigned short*)d_ws;                  // 32 MB
  unsigned short* wb = xb + (size_t)M_DIM * K_DIM;             // 6 MB
  unsigned short* kvq = wb + (size_t)N_DIM * K_DIM;            // 96 MB

  convert_kernel<<<M_DIM + N_DIM, 256, 0, stream>>>(x, Wk, Wv, Wq, xb, wb);
  gemm_kernel<<<(M_DIM / BM) * (N_DIM / BN), 256, 0, stream>>>(xb, wb, kvq);
  scan_kernel<<<B_DIM * NB / 8, 64, 0, stream>>>(kvq, out);
}

// Round 3
// 774.355 us; speedup vs baseline: 1.8959x; 1.2136x over previous
//
#include <hip/hip_runtime.h>
#include <hip/hip_bf16.h>
#include <stdint.h>

// Problem constants
#define T_DIM 2048
#define B_DIM 8
#define D_DIM 1024
#define NSTATE 1024
#define BLKSZ 8
#define NB 128
#define M_DIM (T_DIM * B_DIM)   // 16384
#define N_DIM (3 * NSTATE)      // 3072 (k | v | q concatenated)
#define K_DIM D_DIM             // 1024

typedef __bf16 bf16x8 __attribute__((ext_vector_type(8)));
typedef float f32x4 __attribute__((ext_vector_type(4)));
typedef unsigned int uintx4 __attribute__((ext_vector_type(4)));

typedef __attribute__((address_space(3))) void lds_void;
typedef __attribute__((address_space(1))) const void glb_void;

__device__ __forceinline__ unsigned short f2bf(float f) {
  unsigned u = __float_as_uint(f);
  u = (u + 0x7FFFu + ((u >> 16) & 1u)) >> 16;  // RNE
  return (unsigned short)u;
}
__device__ __forceinline__ float bf2f(unsigned short h) {
  return __uint_as_float(((unsigned)h) << 16);
}

// async 16B/lane global->LDS; lds dest is wave-uniform base + lane*16
__device__ __forceinline__ void load_lds16(const unsigned short* g,
                                           unsigned short* l) {
  __builtin_amdgcn_global_load_lds((glb_void*)g, (lds_void*)l, 16, 0, 0);
}

// ---------------- Kernel 1: fp32 -> bf16 conversion of x and Wcat ----------
__global__ __launch_bounds__(256) void convert_kernel(
    const float* __restrict__ x, const float* __restrict__ Wk,
    const float* __restrict__ Wv, const float* __restrict__ Wq,
    unsigned short* __restrict__ xb, unsigned short* __restrict__ wb) {
  size_t idx = (size_t)blockIdx.x * blockDim.x + threadIdx.x;  // one per 4 elems
  size_t row = idx >> 8;          // 256 chunks of 4 per 1024-row
  int c4 = (int)(idx & 255) * 4;
  const float* src;
  unsigned short* dst;
  if (row < (size_t)M_DIM) {
    src = x + row * K_DIM;
    dst = xb + row * K_DIM;
  } else {
    size_t r = row - M_DIM;
    const float* w = (r < 1024) ? Wk : (r < 2048 ? Wv : Wq);
    src = w + (r & 1023) * K_DIM;
    dst = wb + r * K_DIM;
  }
  float4 v = *(const float4*)(src + c4);
  ushort4 o;
  o.x = f2bf(v.x); o.y = f2bf(v.y); o.z = f2bf(v.z); o.w = f2bf(v.w);
  *(ushort4*)(dst + c4) = o;
}

// ---------------- Kernel 2: bf16 MFMA GEMM  C[M][N] = X[M][K] * W[N][K]^T ---
// global_load_lds staging (m97 structure) with XOR-swizzled unpadded LDS:
// LDS(row, blk16) holds global(row, blk16 ^ ((row>>1)&3)); 16B blocks.
// Both staging and ds_read_b128 fragment reads are 2-way bank-aliased (free).
#define BM 128
#define BN 128
#define BK 32

__global__ __launch_bounds__(256) void gemm_kernel(
    const unsigned short* __restrict__ A,     // [M][K] bf16
    const unsigned short* __restrict__ Bmat,  // [N][K] bf16
    unsigned short* __restrict__ C) {         // [M][N] bf16
  __shared__ unsigned short As[BM * BK];  // 8 KB, unpadded, swizzled
  __shared__ unsigned short Bs[BN * BK];  // 8 KB

  const int tid = threadIdx.x;
  const int nTiles = N_DIM / BN;  // 24
  const int nTile = blockIdx.x % nTiles;
  const int mTile = blockIdx.x / nTiles;
  const int m0 = mTile * BM, n0 = nTile * BN;

  const int lane = tid & 63, wave = tid >> 6;
  const int wm = wave >> 1, wn = wave & 1;  // 2x2 wave grid, 64x64 per wave
  const int l15 = lane & 15, quad = lane >> 4;
  const int sw = quad ^ ((l15 >> 1) & 3);   // de-swizzle for fragment reads

  // staging: chunk = 16 rows x 64B; lane covers (row 16c + l/4, blk16 (l&3)^((l>>3)&3))
  const int srow = lane >> 2;
  const int sblk = (lane & 3) ^ ((lane >> 3) & 3);
  const int c0 = wave, c1 = wave + 4;  // this wave's two chunks per matrix

  const unsigned short* gA0 = A + (size_t)(m0 + c0 * 16 + srow) * K_DIM + sblk * 8;
  const unsigned short* gA1 = A + (size_t)(m0 + c1 * 16 + srow) * K_DIM + sblk * 8;
  const unsigned short* gB0 = Bmat + (size_t)(n0 + c0 * 16 + srow) * K_DIM + sblk * 8;
  const unsigned short* gB1 = Bmat + (size_t)(n0 + c1 * 16 + srow) * K_DIM + sblk * 8;

  f32x4 acc[4][4];
#pragma unroll
  for (int mi = 0; mi < 4; mi++)
#pragma unroll
    for (int ni = 0; ni < 4; ni++) acc[mi][ni] = (f32x4){0.f, 0.f, 0.f, 0.f};

  for (int k0 = 0; k0 < K_DIM; k0 += BK) {
    __syncthreads();  // prior iter's ds_reads complete before overwrite
    load_lds16(gA0 + k0, As + c0 * 512);
    load_lds16(gA1 + k0, As + c1 * 512);
    load_lds16(gB0 + k0, Bs + c0 * 512);
    load_lds16(gB1 + k0, Bs + c1 * 512);
    __syncthreads();  // drains vmcnt: loads have landed

    bf16x8 af[4], bfr[4];
#pragma unroll
    for (int mi = 0; mi < 4; mi++) {
      uintx4 r = *(const uintx4*)(As + (wm * 64 + mi * 16 + l15) * BK + sw * 8);
      af[mi] = __builtin_bit_cast(bf16x8, r);
    }
#pragma unroll
    for (int ni = 0; ni < 4; ni++) {
      uintx4 r = *(const uintx4*)(Bs + (wn * 64 + ni * 16 + l15) * BK + sw * 8);
      bfr[ni] = __builtin_bit_cast(bf16x8, r);
    }
#pragma unroll
    for (int mi = 0; mi < 4; mi++)
#pragma unroll
      for (int ni = 0; ni < 4; ni++)
        acc[mi][ni] = __builtin_amdgcn_mfma_f32_16x16x32_bf16(
            af[mi], bfr[ni], acc[mi][ni], 0, 0, 0);
  }

#pragma unroll
  for (int mi = 0; mi < 4; mi++) {
#pragma unroll
    for (int ni = 0; ni < 4; ni++) {
      int col = n0 + wn * 64 + ni * 16 + l15;
#pragma unroll
      for (int r = 0; r < 4; r++) {
        int rowg = m0 + wm * 64 + mi * 16 + quad * 4 + r;
        C[(size_t)rowg * N_DIM + col] = f2bf(acc[mi][ni][r]);
      }
    }
  }
}

// ---------------- Kernel 3: sequential scan, shuffle-free, deep prefetch ---
// One lane per (chain, row i), chain = (b, nb); lane holds S[i][0..7] in regs.
// Prefetch ring of depth 4 hides HBM latency (only 128 waves -> no TLP).

__device__ __forceinline__ void unpack8(uintx4 u, float* f) {
#pragma unroll
  for (int n = 0; n < 4; n++) {
    unsigned w = u[n];
    f[2 * n] = __uint_as_float(w << 16);
    f[2 * n + 1] = __uint_as_float(w & 0xffff0000u);
  }
}

__device__ __forceinline__ float dot8(const float* a, const float* b) {
  float s01 = fmaf(a[1], b[1], a[0] * b[0]);
  float s23 = fmaf(a[3], b[3], a[2] * b[2]);
  float s45 = fmaf(a[5], b[5], a[4] * b[4]);
  float s67 = fmaf(a[7], b[7], a[6] * b[6]);
  return (s01 + s23) + (s45 + s67);
}

#define C_2LOG2E 2.8853900817779268f   // 2*log2(e)
#define C_LOG2E  1.4426950408889634f
#define PF 4

__global__ __launch_bounds__(64) void scan_kernel(
    const unsigned short* __restrict__ kvq,  // [T*B][3072] bf16 (k|v|q)
    float* __restrict__ out) {               // outputs then S_final
  const int blk = blockIdx.x;          // 0..127
  const int b = blk >> 4;              // 0..7
  const int nb0 = (blk & 15) * 8;      // first nb of this wave
  const int lane = threadIdx.x;
  const int c = lane >> 3;             // chain within wave (0..7)
  const int i = lane & 7;              // row within 8x8 state
  const int nb = nb0 + c;

  const size_t stride = (size_t)B_DIM * N_DIM;  // elems per t
  const size_t koff = (size_t)b * N_DIM + nb * BLKSZ;
  const size_t qoff = koff + 2 * NSTATE;
  const size_t voff = koff + NSTATE + i;

  float S[8];
#pragma unroll
  for (int j = 0; j < 8; j++) S[j] = 0.f;

  uintx4 kb[PF], qb[PF];
  unsigned short vb[PF];
#pragma unroll
  for (int p = 0; p < PF; p++) {
    const unsigned short* sp = kvq + (size_t)p * stride;
    kb[p] = *(const uintx4*)(sp + koff);
    qb[p] = *(const uintx4*)(sp + qoff);
    vb[p] = sp[voff];
  }

  float* outp = out + (size_t)b * NSTATE + (size_t)nb * BLKSZ + i;

  for (int t = 0; t < T_DIM; t += PF) {
#pragma unroll
    for (int u = 0; u < PF; u++) {
      float kf[8], qf[8];
      unpack8(kb[u], kf);
      unpack8(qb[u], qf);
      float vi = bf2f(vb[u]);

      int s = t + u + PF;               // prefetch step s into slot u
      s = (s < T_DIM) ? s : (T_DIM - 1);
      const unsigned short* sp = kvq + (size_t)s * stride;
      kb[u] = *(const uintx4*)(sp + koff);
      qb[u] = *(const uintx4*)(sp + qoff);
      vb[u] = sp[voff];

      // rs = 1/(||k|| + 1e-6)
      float nrm = dot8(kf, kf);
      float rs = __builtin_amdgcn_rcpf(__builtin_amdgcn_sqrtf(nrm) + 1e-6f);
      // delta_i*rs = (v_i - rs*dot(S_i,k)) * rs
      float r = dot8(S, kf);
      float scale = (vi - r * rs) * rs;
      // S_j = tanh(S_j + scale*k_j) = 1 - 2/(exp2(x*2log2e)+1)
#pragma unroll
      for (int j = 0; j < 8; j++) {
        float pre = fmaf(scale, kf[j], S[j]);
        float e = __builtin_amdgcn_exp2f(pre * C_2LOG2E);
        S[j] = fmaf(-2.f, __builtin_amdgcn_rcpf(e + 1.f), 1.f);
      }
      // z_i = dot(S_i, q);  out = z^2 * sigmoid(z)
      float z = dot8(S, qf);
      float sig = __builtin_amdgcn_rcpf(1.f + __builtin_amdgcn_exp2f(-z * C_LOG2E));
      outp[(size_t)(t + u) * (B_DIM * NSTATE)] = z * z * sig;
    }
  }

  // S_final: [B][NB][8][8]; lane (c,i) holds row i -> 8 consecutive floats
  float* sf = out + (size_t)T_DIM * B_DIM * NSTATE +
              (size_t)(b * NB + nb) * 64 + i * 8;
  *(float4*)(sf + 0) = make_float4(S[0], S[1], S[2], S[3]);
  *(float4*)(sf + 4) = make_float4(S[4], S[5], S[6], S[7]);
}

// ---------------- launch ---------------------------------------------------
extern "C" void kernel_launch(void* const* d_in, const int* in_sizes, int n_in,
                              void* d_out, int out_size, void* d_ws,
                              size_t ws_size, hipStream_t stream) {
  const float* x = (const float*)d_in[0];
  const float* Wk = (const float*)d_in[1];
  const float* Wv = (const float*)d_in[2];
  const float* Wq = (const float*)d_in[3];
  float* out = (float*)d_out;

  unsigned short* xb = (unsigned short*)d_ws;                  // 32 MB
  unsigned short* wb = xb + (size_t)M_DIM * K_DIM;             // 6 MB
  unsigned short* kvq = wb + (size_t)N_DIM * K_DIM;            // 96 MB

  convert_kernel<<<M_DIM + N_DIM, 256, 0, stream>>>(x, Wk, Wv, Wq, xb, wb);
  gemm_kernel<<<(M_DIM / BM) * (N_DIM / BN), 256, 0, stream>>>(xb, wb, kvq);
  scan_kernel<<<B_DIM * NB / 8, 64, 0, stream>>>(kvq, out);
}

// Round 4
// 600.640 us; speedup vs baseline: 2.4442x; 1.2892x over previous
//
#include <hip/hip_runtime.h>
#include <hip/hip_bf16.h>
#include <stdint.h>

// Problem constants
#define T_DIM 2048
#define B_DIM 8
#define D_DIM 1024
#define NSTATE 1024
#define BLKSZ 8
#define NB 128
#define M_DIM (T_DIM * B_DIM)   // 16384
#define N_DIM (3 * NSTATE)      // 3072 (k | v | q concatenated)
#define K_DIM D_DIM             // 1024

typedef __bf16 bf16x8 __attribute__((ext_vector_type(8)));
typedef float f32x4 __attribute__((ext_vector_type(4)));
typedef unsigned int uintx4 __attribute__((ext_vector_type(4)));

typedef __attribute__((address_space(3))) void lds_void;
typedef __attribute__((address_space(1))) const void glb_void;

__device__ __forceinline__ unsigned short f2bf(float f) {
  unsigned u = __float_as_uint(f);
  u = (u + 0x7FFFu + ((u >> 16) & 1u)) >> 16;  // RNE
  return (unsigned short)u;
}
__device__ __forceinline__ float bf2f(unsigned short h) {
  return __uint_as_float(((unsigned)h) << 16);
}

__device__ __forceinline__ void load_lds16(const unsigned short* g,
                                           unsigned short* l) {
  __builtin_amdgcn_global_load_lds((glb_void*)g, (lds_void*)l, 16, 0, 0);
}

__device__ __forceinline__ void unpack8(uintx4 u, float* f) {
#pragma unroll
  for (int n = 0; n < 4; n++) {
    unsigned w = u[n];
    f[2 * n] = __uint_as_float(w << 16);
    f[2 * n + 1] = __uint_as_float(w & 0xffff0000u);
  }
}

__device__ __forceinline__ float dot8(const float* a, const float* b) {
  float s01 = fmaf(a[1], b[1], a[0] * b[0]);
  float s23 = fmaf(a[3], b[3], a[2] * b[2]);
  float s45 = fmaf(a[5], b[5], a[4] * b[4]);
  float s67 = fmaf(a[7], b[7], a[6] * b[6]);
  return (s01 + s23) + (s45 + s67);
}

// ---------------- Kernel 1: fp32 -> bf16 conversion of x and Wcat ----------
__global__ __launch_bounds__(256) void convert_kernel(
    const float* __restrict__ x, const float* __restrict__ Wk,
    const float* __restrict__ Wv, const float* __restrict__ Wq,
    unsigned short* __restrict__ xb, unsigned short* __restrict__ wb) {
  size_t idx = (size_t)blockIdx.x * blockDim.x + threadIdx.x;
  size_t row = idx >> 8;
  int c4 = (int)(idx & 255) * 4;
  const float* src;
  unsigned short* dst;
  if (row < (size_t)M_DIM) {
    src = x + row * K_DIM;
    dst = xb + row * K_DIM;
  } else {
    size_t r = row - M_DIM;
    const float* w = (r < 1024) ? Wk : (r < 2048 ? Wv : Wq);
    src = w + (r & 1023) * K_DIM;
    dst = wb + r * K_DIM;
  }
  float4 v = *(const float4*)(src + c4);
  ushort4 o;
  o.x = f2bf(v.x); o.y = f2bf(v.y); o.z = f2bf(v.z); o.w = f2bf(v.w);
  *(ushort4*)(dst + c4) = o;
}

// ---------------- Kernel 2: bf16 MFMA GEMM, packed-layout epilogue ---------
// C logical [row][3072] is stored packed: pk[row][nb][seg][j], seg 0=k,1=v,2=q,
// 24 ushorts (48 B) per (row, nb) so one chain-step is one cache line region.
#define BM 128
#define BN 128
#define BK 32

__global__ __launch_bounds__(256) void gemm_kernel(
    const unsigned short* __restrict__ A,     // [M][K] bf16
    const unsigned short* __restrict__ Bmat,  // [N][K] bf16
    unsigned short* __restrict__ pk) {        // packed [M][128][24]
  __shared__ unsigned short As[BM * BK];  // swizzled, unpadded
  __shared__ unsigned short Bs[BN * BK];

  const int tid = threadIdx.x;
  const int nTiles = N_DIM / BN;  // 24
  const int nTile = blockIdx.x % nTiles;
  const int mTile = blockIdx.x / nTiles;
  const int m0 = mTile * BM, n0 = nTile * BN;

  const int lane = tid & 63, wave = tid >> 6;
  const int wm = wave >> 1, wn = wave & 1;
  const int l15 = lane & 15, quad = lane >> 4;
  const int sw = quad ^ ((l15 >> 1) & 3);

  const int srow = lane >> 2;
  const int sblk = (lane & 3) ^ ((lane >> 3) & 3);
  const int c0 = wave, c1 = wave + 4;

  const unsigned short* gA0 = A + (size_t)(m0 + c0 * 16 + srow) * K_DIM + sblk * 8;
  const unsigned short* gA1 = A + (size_t)(m0 + c1 * 16 + srow) * K_DIM + sblk * 8;
  const unsigned short* gB0 = Bmat + (size_t)(n0 + c0 * 16 + srow) * K_DIM + sblk * 8;
  const unsigned short* gB1 = Bmat + (size_t)(n0 + c1 * 16 + srow) * K_DIM + sblk * 8;

  f32x4 acc[4][4];
#pragma unroll
  for (int mi = 0; mi < 4; mi++)
#pragma unroll
    for (int ni = 0; ni < 4; ni++) acc[mi][ni] = (f32x4){0.f, 0.f, 0.f, 0.f};

  for (int k0 = 0; k0 < K_DIM; k0 += BK) {
    __syncthreads();
    load_lds16(gA0 + k0, As + c0 * 512);
    load_lds16(gA1 + k0, As + c1 * 512);
    load_lds16(gB0 + k0, Bs + c0 * 512);
    load_lds16(gB1 + k0, Bs + c1 * 512);
    __syncthreads();

    bf16x8 af[4], bfr[4];
#pragma unroll
    for (int mi = 0; mi < 4; mi++) {
      uintx4 r = *(const uintx4*)(As + (wm * 64 + mi * 16 + l15) * BK + sw * 8);
      af[mi] = __builtin_bit_cast(bf16x8, r);
    }
#pragma unroll
    for (int ni = 0; ni < 4; ni++) {
      uintx4 r = *(const uintx4*)(Bs + (wn * 64 + ni * 16 + l15) * BK + sw * 8);
      bfr[ni] = __builtin_bit_cast(bf16x8, r);
    }
#pragma unroll
    for (int mi = 0; mi < 4; mi++)
#pragma unroll
      for (int ni = 0; ni < 4; ni++)
        acc[mi][ni] = __builtin_amdgcn_mfma_f32_16x16x32_bf16(
            af[mi], bfr[ni], acc[mi][ni], 0, 0, 0);
  }

#pragma unroll
  for (int mi = 0; mi < 4; mi++) {
#pragma unroll
    for (int ni = 0; ni < 4; ni++) {
      const int col = n0 + wn * 64 + ni * 16 + l15;
      const int seg = col >> 10;        // 0=k 1=v 2=q
      const int wcol = col & 1023;
      const size_t cbase = (size_t)(wcol >> 3) * 24 + seg * 8 + (wcol & 7);
#pragma unroll
      for (int r = 0; r < 4; r++) {
        int rowg = m0 + wm * 64 + mi * 16 + quad * 4 + r;
        pk[(size_t)rowg * 3072 + cbase] = f2bf(acc[mi][ni][r]);
      }
    }
  }
}

// ---------------- Kernel 2b: in-place k normalization ----------------------
// One thread per (row, nb): kn = k / (||k|| + 1e-6), bf16 in place.
__global__ __launch_bounds__(256) void knorm_kernel(unsigned short* __restrict__ pk) {
  size_t idx = (size_t)blockIdx.x * 256 + threadIdx.x;  // row*128+nb, < 2M
  unsigned short* p = pk + idx * 24;
  uintx4 k4 = *(const uintx4*)p;
  float kf[8];
  unpack8(k4, kf);
  float nrm = dot8(kf, kf);
  float rs = __builtin_amdgcn_rcpf(__builtin_amdgcn_sqrtf(nrm) + 1e-6f);
  uintx4 o;
#pragma unroll
  for (int n = 0; n < 4; n++) {
    unsigned lo = f2bf(kf[2 * n] * rs);
    unsigned hi = f2bf(kf[2 * n + 1] * rs);
    o[n] = lo | (hi << 16);
  }
  *(uintx4*)p = o;
}

// ---------------- Kernel 3: scan, one lane per state element ---------------
// chain = (b, nb) per 64-lane wave; lane (i,j) holds S[i][j] (scalar).
// Reductions over j (8 lanes) via DPP: xor1, xor2, row_half_mirror.
#define C_2LOG2E 2.8853900817779268f   // 2*log2(e)
#define C_LOG2E  1.4426950408889634f
#define PF 8

template <int CTRL>
__device__ __forceinline__ float dpp_add(float x) {
  int y = __builtin_amdgcn_update_dpp(0, __float_as_int(x), CTRL, 0xF, 0xF, true);
  return x + __int_as_float(y);
}
__device__ __forceinline__ float reduce8(float x) {
  x = dpp_add<0xB1>(x);   // quad_perm(1,0,3,2): lane ^ 1
  x = dpp_add<0x4E>(x);   // quad_perm(2,3,0,1): lane ^ 2
  x = dpp_add<0x141>(x);  // row_half_mirror: crosses quads within 8-group
  return x;
}

__global__ __launch_bounds__(64) void scan_kernel(
    const unsigned short* __restrict__ pk,  // packed [T*B][128][kn8|v8|q8]
    float* __restrict__ out) {
  const int chain = blockIdx.x;        // b*128+nb
  const int b = chain >> 7, nb = chain & 127;
  const int lane = threadIdx.x;
  const int i = lane >> 3, j = lane & 7;

  const size_t tstride = (size_t)B_DIM * NB * 24;  // ushorts per t-slab
  const unsigned short* p = pk + (size_t)chain * 24;
  const int ko = j, vo = 8 + i, qo = 16 + j;

  float S = 0.f;
  unsigned short kb[PF], vb[PF], qb[PF];
#pragma unroll
  for (int s = 0; s < PF; s++) {
    const unsigned short* sp = p + (size_t)s * tstride;
    kb[s] = sp[ko]; vb[s] = sp[vo]; qb[s] = sp[qo];
  }
  const unsigned short* pref = p + (size_t)PF * tstride;

  float* outp = out + (size_t)b * NSTATE + nb * BLKSZ + i;
  const bool writer = (j == 0);

  for (int t = 0; t < T_DIM; t += PF) {
#pragma unroll
    for (int u = 0; u < PF; u++) {
      float kf = bf2f(kb[u]);
      float vf = bf2f(vb[u]);
      float qf = bf2f(qb[u]);

      // prefetch step t+u+PF into slot u (pointer clamps at last slab)
      kb[u] = pref[ko]; vb[u] = pref[vo]; qb[u] = pref[qo];
      pref += (t + u + PF < T_DIM - 1) ? tstride : 0;

      // retrieved_i = sum_j S[i][j]*kn[j]  (k pre-normalized)
      float r = reduce8(S * kf);
      float delta = vf - r;
      // S = tanh(S + delta*kn)
      float arg = fmaf(delta, kf, S);
      float e = __builtin_amdgcn_exp2f(arg * C_2LOG2E);
      S = fmaf(-2.f, __builtin_amdgcn_rcpf(e + 1.f), 1.f);
      // z_i = sum_j S[i][j]*q[j]; out = z^2 * sigmoid(z)
      float z = reduce8(S * qf);
      float sig = __builtin_amdgcn_rcpf(1.f + __builtin_amdgcn_exp2f(-z * C_LOG2E));
      float o = z * z * sig;
      if (writer) outp[(size_t)(t + u) * (B_DIM * NSTATE)] = o;
    }
  }

  // S_final: [B][NB][8][8]; lane (i,j) -> element i*8+j, coalesced
  out[(size_t)T_DIM * B_DIM * NSTATE + (size_t)chain * 64 + lane] = S;
}

// ---------------- launch ---------------------------------------------------
extern "C" void kernel_launch(void* const* d_in, const int* in_sizes, int n_in,
                              void* d_out, int out_size, void* d_ws,
                              size_t ws_size, hipStream_t stream) {
  const float* x = (const float*)d_in[0];
  const float* Wk = (const float*)d_in[1];
  const float* Wv = (const float*)d_in[2];
  const float* Wq = (const float*)d_in[3];
  float* out = (float*)d_out;

  unsigned short* xb = (unsigned short*)d_ws;                  // 32 MB
  unsigned short* wb = xb + (size_t)M_DIM * K_DIM;             // 6 MB
  unsigned short* pk = wb + (size_t)N_DIM * K_DIM;             // 96 MB packed

  convert_kernel<<<M_DIM + N_DIM, 256, 0, stream>>>(x, Wk, Wv, Wq, xb, wb);
  gemm_kernel<<<(M_DIM / BM) * (N_DIM / BN), 256, 0, stream>>>(xb, wb, pk);
  knorm_kernel<<<(M_DIM * NB) / 256, 256, 0, stream>>>(pk);
  scan_kernel<<<B_DIM * NB, 64, 0, stream>>>(pk, out);
}

// Round 5
// 575.390 us; speedup vs baseline: 2.5515x; 1.0439x over previous
//
#include <hip/hip_runtime.h>
#include <hip/hip_bf16.h>
#include <stdint.h>

// Problem constants
#define T_DIM 2048
#define B_DIM 8
#define D_DIM 1024
#define NSTATE 1024
#define BLKSZ 8
#define NB 128
#define M_DIM (T_DIM * B_DIM)   // 16384
#define N_DIM (3 * NSTATE)      // 3072 (k | v | q concatenated)
#define K_DIM D_DIM             // 1024

typedef __bf16 bf16x8 __attribute__((ext_vector_type(8)));
typedef float f32x4 __attribute__((ext_vector_type(4)));
typedef unsigned int uintx4 __attribute__((ext_vector_type(4)));

typedef __attribute__((address_space(3))) void lds_void;
typedef __attribute__((address_space(1))) const void glb_void;

__device__ __forceinline__ unsigned short f2bf(float f) {
  unsigned u = __float_as_uint(f);
  u = (u + 0x7FFFu + ((u >> 16) & 1u)) >> 16;  // RNE
  return (unsigned short)u;
}
__device__ __forceinline__ float bf2f(unsigned short h) {
  return __uint_as_float(((unsigned)h) << 16);
}

__device__ __forceinline__ void load_lds16(const unsigned short* g,
                                           unsigned short* l) {
  __builtin_amdgcn_global_load_lds((glb_void*)g, (lds_void*)l, 16, 0, 0);
}

// 8-lane butterfly sum-broadcast via DPP (groups = physical lanes 8k..8k+7)
template <int CTRL>
__device__ __forceinline__ float dpp_add(float x) {
  int y = __builtin_amdgcn_update_dpp(0, __float_as_int(x), CTRL, 0xF, 0xF, true);
  return x + __int_as_float(y);
}
__device__ __forceinline__ float reduce8(float x) {
  x = dpp_add<0xB1>(x);   // quad_perm(1,0,3,2): lane ^ 1
  x = dpp_add<0x4E>(x);   // quad_perm(2,3,0,1): lane ^ 2
  x = dpp_add<0x141>(x);  // row_half_mirror: crosses quads within 8-group
  return x;
}

// ---------------- Kernel 1: fp32 -> bf16 conversion of x and Wcat ----------
__global__ __launch_bounds__(256) void convert_kernel(
    const float* __restrict__ x, const float* __restrict__ Wk,
    const float* __restrict__ Wv, const float* __restrict__ Wq,
    unsigned short* __restrict__ xb, unsigned short* __restrict__ wb) {
  size_t idx = (size_t)blockIdx.x * blockDim.x + threadIdx.x;
  size_t row = idx >> 8;
  int c4 = (int)(idx & 255) * 4;
  const float* src;
  unsigned short* dst;
  if (row < (size_t)M_DIM) {
    src = x + row * K_DIM;
    dst = xb + row * K_DIM;
  } else {
    size_t r = row - M_DIM;
    const float* w = (r < 1024) ? Wk : (r < 2048 ? Wv : Wq);
    src = w + (r & 1023) * K_DIM;
    dst = wb + r * K_DIM;
  }
  float4 v = *(const float4*)(src + c4);
  ushort4 o;
  o.x = f2bf(v.x); o.y = f2bf(v.y); o.z = f2bf(v.z); o.w = f2bf(v.w);
  *(ushort4*)(dst + c4) = o;
}

// ---------------- Kernel 2: bf16 MFMA GEMM, chain-major packed epilogue ----
// pk[chain][t][seg][j]: chain = b*128+nb, record = 24 ushorts (k8|v8|q8).
// k is normalized IN the epilogue (fp32, DPP reduce over the 8 j-lanes).
#define BM 128
#define BN 128
#define BK 32

__global__ __launch_bounds__(256) void gemm_kernel(
    const unsigned short* __restrict__ A,     // [M][K] bf16
    const unsigned short* __restrict__ Bmat,  // [N][K] bf16
    unsigned short* __restrict__ pk) {        // packed [1024][2048][24]
  __shared__ unsigned short As[BM * BK];  // swizzled, unpadded
  __shared__ unsigned short Bs[BN * BK];

  const int tid = threadIdx.x;
  const int nTiles = N_DIM / BN;  // 24
  const int nTile = blockIdx.x % nTiles;
  const int mTile = blockIdx.x / nTiles;
  const int m0 = mTile * BM, n0 = nTile * BN;

  const int lane = tid & 63, wave = tid >> 6;
  const int wm = wave >> 1, wn = wave & 1;
  const int l15 = lane & 15, quad = lane >> 4;
  const int sw = quad ^ ((l15 >> 1) & 3);

  const int srow = lane >> 2;
  const int sblk = (lane & 3) ^ ((lane >> 3) & 3);
  const int c0 = wave, c1 = wave + 4;

  const unsigned short* gA0 = A + (size_t)(m0 + c0 * 16 + srow) * K_DIM + sblk * 8;
  const unsigned short* gA1 = A + (size_t)(m0 + c1 * 16 + srow) * K_DIM + sblk * 8;
  const unsigned short* gB0 = Bmat + (size_t)(n0 + c0 * 16 + srow) * K_DIM + sblk * 8;
  const unsigned short* gB1 = Bmat + (size_t)(n0 + c1 * 16 + srow) * K_DIM + sblk * 8;

  f32x4 acc[4][4];
#pragma unroll
  for (int mi = 0; mi < 4; mi++)
#pragma unroll
    for (int ni = 0; ni < 4; ni++) acc[mi][ni] = (f32x4){0.f, 0.f, 0.f, 0.f};

  for (int k0 = 0; k0 < K_DIM; k0 += BK) {
    __syncthreads();
    load_lds16(gA0 + k0, As + c0 * 512);
    load_lds16(gA1 + k0, As + c1 * 512);
    load_lds16(gB0 + k0, Bs + c0 * 512);
    load_lds16(gB1 + k0, Bs + c1 * 512);
    __syncthreads();

    bf16x8 af[4], bfr[4];
#pragma unroll
    for (int mi = 0; mi < 4; mi++) {
      uintx4 r = *(const uintx4*)(As + (wm * 64 + mi * 16 + l15) * BK + sw * 8);
      af[mi] = __builtin_bit_cast(bf16x8, r);
    }
#pragma unroll
    for (int ni = 0; ni < 4; ni++) {
      uintx4 r = *(const uintx4*)(Bs + (wn * 64 + ni * 16 + l15) * BK + sw * 8);
      bfr[ni] = __builtin_bit_cast(bf16x8, r);
    }
#pragma unroll
    for (int mi = 0; mi < 4; mi++)
#pragma unroll
      for (int ni = 0; ni < 4; ni++)
        acc[mi][ni] = __builtin_amdgcn_mfma_f32_16x16x32_bf16(
            af[mi], bfr[ni], acc[mi][ni], 0, 0, 0);
  }

  // Epilogue: scatter into chain-major records; normalize k-segment rows.
#pragma unroll
  for (int mi = 0; mi < 4; mi++) {
#pragma unroll
    for (int ni = 0; ni < 4; ni++) {
      const int col = n0 + wn * 64 + ni * 16 + l15;
      const int seg = col >> 10;        // 0=k 1=v 2=q (uniform per block)
      const int wcol = col & 1023;
      const int nbq = wcol >> 3, jq = wcol & 7;
#pragma unroll
      for (int r = 0; r < 4; r++) {
        const int rowg = m0 + wm * 64 + mi * 16 + quad * 4 + r;
        const int t = rowg >> 3, bq = rowg & 7;
        float val = acc[mi][ni][r];
        if (seg == 0) {  // wave-uniform branch
          float ss = reduce8(val * val);  // ||k||^2 over the 8 j-lanes
          float rs = __builtin_amdgcn_rcpf(__builtin_amdgcn_sqrtf(ss) + 1e-6f);
          val *= rs;
        }
        const size_t addr =
            ((size_t)(bq * NB + nbq) * T_DIM + t) * 24 + seg * 8 + jq;
        pk[addr] = f2bf(val);
      }
    }
  }
}

// ---------------- Kernel 3: scan, element-per-lane, contiguous stream ------
// One chain (b,nb) per 64-lane wave; lane (i,j) holds S[i][j].
// pk stream is chain-private and contiguous: 48 B/step -> L1-resident.
#define C_2LOG2E 2.8853900817779268f   // 2*log2(e)
#define C_LOG2E  1.4426950408889634f
#define PF 8

__device__ __forceinline__ float step_update(float& S, float kf, float vf,
                                             float qf) {
  // retrieved_i = sum_j S[i][j]*kn[j]  (k pre-normalized)
  float r = reduce8(S * kf);
  float delta = vf - r;
  // S = tanh(S + delta*kn)
  float arg = fmaf(delta, kf, S);
  float e = __builtin_amdgcn_exp2f(arg * C_2LOG2E);
  S = fmaf(-2.f, __builtin_amdgcn_rcpf(e + 1.f), 1.f);
  // z_i = sum_j S[i][j]*q[j]; out = z^2 * sigmoid(z)
  float z = reduce8(S * qf);
  float sig = __builtin_amdgcn_rcpf(1.f + __builtin_amdgcn_exp2f(-z * C_LOG2E));
  return z * z * sig;
}

__global__ __launch_bounds__(64) void scan_kernel(
    const unsigned short* __restrict__ pk,  // [1024][2048][kn8|v8|q8]
    float* __restrict__ out) {
  const int chain = blockIdx.x;        // b*128+nb
  const int b = chain >> 7, nb = chain & 127;
  const int lane = threadIdx.x;
  const int i = lane >> 3, j = lane & 7;

  const unsigned short* base = pk + (size_t)chain * T_DIM * 24;
  const int ko = j, vo = 8 + i, qo = 16 + j;

  float S = 0.f;
  unsigned short kb[PF], vb[PF], qb[PF];
#pragma unroll
  for (int s = 0; s < PF; s++) {
    const unsigned short* rec = base + s * 24;
    kb[s] = rec[ko]; vb[s] = rec[vo]; qb[s] = rec[qo];
  }

  float* outp = out + (size_t)b * NSTATE + nb * BLKSZ + i;
  const bool writer = (j == 0);

  for (int t = 0; t < T_DIM - PF; t += PF) {
#pragma unroll
    for (int u = 0; u < PF; u++) {
      float kf = bf2f(kb[u]);
      float vf = bf2f(vb[u]);
      float qf = bf2f(qb[u]);
      const unsigned short* rec = base + (size_t)(t + u + PF) * 24;
      kb[u] = rec[ko]; vb[u] = rec[vo]; qb[u] = rec[qo];
      float o = step_update(S, kf, vf, qf);
      if (writer) outp[(size_t)(t + u) * (B_DIM * NSTATE)] = o;
    }
  }
  // tail: consume last PF steps, no prefetch
#pragma unroll
  for (int u = 0; u < PF; u++) {
    float o = step_update(S, bf2f(kb[u]), bf2f(vb[u]), bf2f(qb[u]));
    if (writer) outp[(size_t)(T_DIM - PF + u) * (B_DIM * NSTATE)] = o;
  }

  // S_final: [B][NB][8][8]; lane (i,j) -> element i*8+j, coalesced
  out[(size_t)T_DIM * B_DIM * NSTATE + (size_t)chain * 64 + lane] = S;
}

// ---------------- launch ---------------------------------------------------
extern "C" void kernel_launch(void* const* d_in, const int* in_sizes, int n_in,
                              void* d_out, int out_size, void* d_ws,
                              size_t ws_size, hipStream_t stream) {
  const float* x = (const float*)d_in[0];
  const float* Wk = (const float*)d_in[1];
  const float* Wv = (const float*)d_in[2];
  const float* Wq = (const float*)d_in[3];
  float* out = (float*)d_out;

  unsigned short* xb = (unsigned short*)d_ws;                  // 32 MiB
  unsigned short* wb = xb + (size_t)M_DIM * K_DIM;             // 6 MiB
  unsigned short* pk = wb + (size_t)N_DIM * K_DIM;             // 96 MiB packed

  convert_kernel<<<M_DIM + N_DIM, 256, 0, stream>>>(x, Wk, Wv, Wq, xb, wb);
  gemm_kernel<<<(M_DIM / BM) * (N_DIM / BN), 256, 0, stream>>>(xb, wb, pk);
  scan_kernel<<<B_DIM * NB, 64, 0, stream>>>(pk, out);
}